// Round 18
// baseline (304.557 us; speedup 1.0000x reference)
//
#include <hip/hip_runtime.h>

typedef unsigned short u16;
typedef __attribute__((ext_vector_type(8))) short bf16x8;
typedef __attribute__((ext_vector_type(4))) float f32x4;
typedef __attribute__((ext_vector_type(4))) u16 u16x4;

#define MFMA16(a, b, c) __builtin_amdgcn_mfma_f32_16x16x32_bf16(a, b, c, 0, 0, 0)

__device__ __forceinline__ u16 f2bf(float f) {
    union { float f; unsigned u; } v; v.f = f;
    unsigned r = (v.u + 0x7FFFu + ((v.u >> 16) & 1u)) >> 16;  // RNE
    return (u16)r;
}

__device__ __forceinline__ void gload_lds16(const void* g, void* l) {
    __builtin_amdgcn_global_load_lds((const __attribute__((address_space(1))) void*)g,
                                     (__attribute__((address_space(3))) void*)l, 16, 0, 0);
}

// ---------- prep: fp32 -> bf16 (optionally scaled) ----------
__global__ __launch_bounds__(256) void cvt_kernel(const float* __restrict__ src,
                                                  u16* __restrict__ dst, int n4, float scale) {
    int i = blockIdx.x * 256 + threadIdx.x;
    if (i >= n4) return;
    f32x4 v = *(const f32x4*)(src + (size_t)i * 4);
    u16x4 o;
#pragma unroll
    for (int j = 0; j < 4; ++j) o[j] = f2bf(v[j] * scale);
    *(u16x4*)(dst + (size_t)i * 4) = o;
}

// ---------- prep: V (8192x512 f32) -> Vt (512x8192 bf16) ----------
__global__ __launch_bounds__(256) void prep_vt(const float* __restrict__ V, u16* __restrict__ Vt) {
    __shared__ float tile[64][65];
    int t = threadIdx.x;
    int n0 = blockIdx.x * 64;
    int d0 = blockIdx.y * 64;
    int tr = t >> 4, tc = t & 15;
#pragma unroll
    for (int p = 0; p < 4; ++p) {
        int n = p * 16 + tr;
        f32x4 v = *(const f32x4*)(V + (size_t)(n0 + n) * 512 + d0 + tc * 4);
#pragma unroll
        for (int j = 0; j < 4; ++j) tile[n][tc * 4 + j] = v[j];
    }
    __syncthreads();
#pragma unroll
    for (int p = 0; p < 4; ++p) {
        int d = p * 16 + tr;
        u16x4 o;
#pragma unroll
        for (int j = 0; j < 4; ++j) o[j] = f2bf(tile[tc * 4 + j][d]);
        *(u16x4*)(Vt + (size_t)(d0 + d) * 8192 + n0 + tc * 4) = o;
    }
}

// ---------- flash attention: BM=64, KVBLK=128, key-split 2, 32-row waves ----------
// R17 barrier skeleton (2 barriers / 128 keys). Wave grid: rs(2 x 32 rows) x ks(4 x 16 keys);
// qf[2][16] = 128 VGPR (32 rows) -> each K A-fragment read feeds 2 MFMAs -> S-phase LDS
// reads halved (K-dup 4 -> 2). exp2 variant: scale pre-multiplied by log2(e), P = exp2(s).
__global__ __launch_bounds__(512) void flash_kernel(
    const u16* __restrict__ Qs, const u16* __restrict__ Kb, const u16* __restrict__ Vt,
    float* __restrict__ Opart, float* __restrict__ lpart) {
    __shared__ __align__(16) u16 lds_k[128 * 512];  // 128 KB single buffer, XOR swizzle
    __shared__ __align__(16) u16 lds_p[64 * 128];   // 16 KB P tile, swizzled per 8-chunk half
    __shared__ float s_l[4][64];

    const int tid = threadIdx.x;
    const int wid = tid >> 6;
    const int lane = tid & 63;
    const int lo = lane & 15;
    const int hi = lane >> 4;
    const int ks4 = wid & 3;   // key strip (4 x 16 keys)
    const int rs = wid >> 2;   // row strip (2 x 32 rows)

    // same-XCD blocks share a key-split (L2 reuse of the K/V stream)
    const int bx = blockIdx.x;
    const int x = bx & 7;
    const int g = bx >> 3;
    const int ks = x >> 2;
    const int mtile = g * 4 + (x & 3);
    const int key0 = ks * 4096;

    // Q fragments (B-operand of swapped S-MFMA): 32 rows (2 row-tiles). 128 VGPR.
    bf16x8 qf[2][16];
#pragma unroll
    for (int rt = 0; rt < 2; ++rt) {
        const u16* qrow = Qs + (size_t)(mtile * 64 + rs * 32 + rt * 16 + lo) * 512 + hi * 8;
#pragma unroll
        for (int kt = 0; kt < 16; ++kt) qf[rt][kt] = *(const bf16x8*)(qrow + kt * 32);
    }

    f32x4 o[4][4];
#pragma unroll
    for (int a = 0; a < 4; ++a)
#pragma unroll
        for (int b = 0; b < 4; ++b) o[a][b] = (f32x4){0.f, 0.f, 0.f, 0.f};
    float lsum0 = 0.f, lsum1 = 0.f;

    // S-read addressing (verified): chunk(kt) = (kt*4+hi) ^ (krow&7); krow = ks4*16+lo
    // (ks4*16 == 0 mod 8 -> identical decomposition). Sub-tile B: +64 rows.
    const int cbase = ((hi ^ (lo & 3)) + ((lo >> 2) & 1) * 4) * 8;
    const int rowA_A = (ks4 * 16 + lo) * 512;
    const int rowA_B = rowA_A + 64 * 512;

    // P-write: row0 = rs*32+lo (rt0), row1 = row0+16 (rt1, same row&7 -> same chunk XOR).
    // keys ks4*16 + hi*4 + r -> chunk16 (ks4*2 + (hi>>1)) ^ (row&7); sub-B +8 chunks (+64 elems).
    const int row0 = rs * 32 + lo;
    const int pwA = row0 * 128 + ((((ks4 << 1) + (hi >> 1)) ^ (row0 & 7)) << 3) + (hi & 1) * 4;

#define STAGE_K(IT)                                                                 \
    {                                                                               \
        const u16* kb_ = Kb + (size_t)(key0 + (IT) * 128) * 512;                    \
        _Pragma("unroll") for (int r_ = 0; r_ < 16; ++r_) {                         \
            int row_ = (wid << 4) + r_;                                             \
            gload_lds16(kb_ + (size_t)row_ * 512 + ((lane ^ (row_ & 7)) << 3),      \
                        &lds_k[row_ * 512]);                                        \
        }                                                                           \
    }

// 16 A-reads feed 32 MFMAs (2 row-tiles per read); 4 indep chains
#define S_COMPUTE(ROWBASE, SE0, SO0, SE1, SO1)                                      \
    {                                                                               \
        const u16* pAe = &lds_k[0] + (ROWBASE) + cbase;                             \
        const u16* pAo = &lds_k[0] + (ROWBASE) + (cbase ^ 32);                      \
        _Pragma("unroll") for (int kt2 = 0; kt2 < 8; ++kt2) {                       \
            bf16x8 ae = *(const bf16x8*)(pAe + kt2 * 64);                           \
            bf16x8 ao = *(const bf16x8*)(pAo + kt2 * 64);                           \
            SE0 = MFMA16(ae, qf[0][2 * kt2], SE0);                                  \
            SE1 = MFMA16(ae, qf[1][2 * kt2], SE1);                                  \
            SO0 = MFMA16(ao, qf[0][2 * kt2 + 1], SO0);                              \
            SO1 = MFMA16(ao, qf[1][2 * kt2 + 1], SO1);                              \
        }                                                                           \
    }

// exp2 + P-write for both row-tiles of one sub-tile; BOFS = 0 (sub-A) or 64 (sub-B)
#define EXP_PW(SRT0, SRT1, BOFS)                                                    \
    {                                                                               \
        u16x4 w0, w1;                                                               \
        _Pragma("unroll") for (int r = 0; r < 4; ++r) {                             \
            float p0 = exp2f((SRT0)[r]);                                            \
            float p1 = exp2f((SRT1)[r]);                                            \
            lsum0 += p0;                                                            \
            lsum1 += p1;                                                            \
            w0[r] = f2bf(p0);                                                       \
            w1[r] = f2bf(p1);                                                       \
        }                                                                           \
        *(u16x4*)(&lds_p[pwA + (BOFS)]) = w0;                                       \
        *(u16x4*)(&lds_p[pwA + 2048 + (BOFS)]) = w1;                                \
    }

// PV sub-tile (identical to R17): CH_OFF = 0 or 8; V frags in VB
#define PV_STEP(CH_OFF, VB)                                                         \
    {                                                                               \
        _Pragma("unroll") for (int mt = 0; mt < 4; ++mt) {                          \
            int m = mt * 16 + lo;                                                   \
            int c0 = (CH_OFF) + (hi ^ (m & 7));                                     \
            int c1 = (CH_OFF) + ((4 + hi) ^ (m & 7));                               \
            bf16x8 pa0 = *(const bf16x8*)(&lds_p[m * 128 + c0 * 8]);                \
            bf16x8 pa1 = *(const bf16x8*)(&lds_p[m * 128 + c1 * 8]);                \
            _Pragma("unroll") for (int nt = 0; nt < 4; ++nt) {                      \
                f32x4 c_ = o[mt][nt];                                               \
                c_ = MFMA16(pa0, VB[nt][0], c_);                                    \
                c_ = MFMA16(pa1, VB[nt][1], c_);                                    \
                o[mt][nt] = c_;                                                     \
            }                                                                       \
        }                                                                           \
    }

#define VB_LOAD(T, KOFF, VB)                                                        \
    {                                                                               \
        _Pragma("unroll") for (int nt = 0; nt < 4; ++nt) {                          \
            const u16* vrow = Vt + (size_t)(wid * 64 + nt * 16 + lo) * 8192 +       \
                              key0 + (T) * 128 + (KOFF) + hi * 8;                   \
            VB[nt][0] = *(const bf16x8*)(vrow);                                     \
            VB[nt][1] = *(const bf16x8*)(vrow + 32);                                \
        }                                                                           \
    }

    // prologue: K(0) -> buffer
    STAGE_K(0)
    asm volatile("s_waitcnt vmcnt(0)\n\ts_barrier" ::: "memory");

    for (int t = 0; t < 32; ++t) {
        // ---- sub-tile A: keys [t*128, +64); 16 reads / 32 MFMAs ----
        f32x4 ae0 = {0.f, 0.f, 0.f, 0.f}, ao0 = ae0, ae1 = ae0, ao1 = ae0;
        __builtin_amdgcn_s_setprio(1);
        S_COMPUTE(rowA_A, ae0, ao0, ae1, ao1)
        __builtin_amdgcn_s_setprio(0);
        f32x4 sA0 = ae0 + ao0, sA1 = ae1 + ao1;
        EXP_PW(sA0, sA1, 0)

        // ---- sub-tile B: keys [t*128+64, +64) ----
        f32x4 be0 = {0.f, 0.f, 0.f, 0.f}, bo0 = be0, be1 = be0, bo1 = be0;
        __builtin_amdgcn_s_setprio(1);
        S_COMPUTE(rowA_B, be0, bo0, be1, bo1)
        __builtin_amdgcn_s_setprio(0);
        f32x4 sB0 = be0 + bo0, sB1 = be1 + bo1;
        EXP_PW(sB0, sB1, 64)

        // ---- P visible AND all lds_k reads retired -> safe to overwrite K buffer ----
        asm volatile("s_waitcnt lgkmcnt(0)\n\ts_barrier" ::: "memory");

        if (t < 31) STAGE_K(t + 1)  // flies under vb loads + PV_A + PV_B

        // vb loads after the S phase (register-budget: qf128 + o64 + one vb32 live)
        {
            bf16x8 vbA[4][2];
            VB_LOAD(t, 0, vbA)
            __builtin_amdgcn_s_setprio(1);
            PV_STEP(0, vbA)
            __builtin_amdgcn_s_setprio(0);
        }
        {
            bf16x8 vbB[4][2];
            VB_LOAD(t, 64, vbB)
            __builtin_amdgcn_s_setprio(1);
            PV_STEP(8, vbB)
            __builtin_amdgcn_s_setprio(0);
        }

        // end barrier: stage(t+1) drained; PV's lds_p reads retired before next P-write
        if (t < 31) asm volatile("s_waitcnt vmcnt(0) lgkmcnt(0)\n\ts_barrier" ::: "memory");
    }

    // ---- epilogue: lsum0/1 cover rows rs*32 + {lo, 16+lo} over strip ks4; reduce over hi ----
    lsum0 += __shfl_xor(lsum0, 16);
    lsum0 += __shfl_xor(lsum0, 32);
    lsum1 += __shfl_xor(lsum1, 16);
    lsum1 += __shfl_xor(lsum1, 32);
    if (lane < 16) {
        s_l[ks4][rs * 32 + lo] = lsum0;
        s_l[ks4][rs * 32 + 16 + lo] = lsum1;
    }
    __syncthreads();

    const int lb = mtile * 2 + ks;  // logical partial index
    {
        float* Ob = Opart + (size_t)lb * (64 * 512);
#pragma unroll
        for (int mt = 0; mt < 4; ++mt)
#pragma unroll
            for (int nt = 0; nt < 4; ++nt)
#pragma unroll
                for (int r = 0; r < 4; ++r) {
                    int row = mt * 16 + hi * 4 + r;
                    int col = wid * 64 + nt * 16 + lo;
                    Ob[row * 512 + col] = o[mt][nt][r];
                }
        if (tid < 64) {
            lpart[lb * 64 + tid] = s_l[0][tid] + s_l[1][tid] + s_l[2][tid] + s_l[3][tid];
        }
    }
}

// ---------- combine the 2 key-split partials: out = (O0+O1)/(l0+l1) ----------
__global__ __launch_bounds__(256) void combine_kernel(const float* __restrict__ Opart,
                                                      const float* __restrict__ lpart,
                                                      float* __restrict__ out) {
    int i = blockIdx.x * 256 + threadIdx.x;  // float4 index; 8192*512/4 = 1048576 total
    int row = i >> 7;
    int c4 = i & 127;
    int mtile = row >> 6, rl = row & 63;
    int b0 = mtile * 2, b1 = b0 + 1;
    float inv = 1.0f / (lpart[b0 * 64 + rl] + lpart[b1 * 64 + rl]);
    f32x4 a = *(const f32x4*)(Opart + (size_t)b0 * 32768 + rl * 512 + c4 * 4);
    f32x4 b = *(const f32x4*)(Opart + (size_t)b1 * 32768 + rl * 512 + c4 * 4);
    f32x4 r = (a + b) * inv;
    *(f32x4*)(out + (size_t)row * 512 + c4 * 4) = r;
}

extern "C" void kernel_launch(void* const* d_in, const int* in_sizes, int n_in,
                              void* d_out, int out_size, void* d_ws, size_t ws_size,
                              hipStream_t stream) {
    const float* Q = (const float*)d_in[0];
    const float* K = (const float*)d_in[1];
    const float* V = (const float*)d_in[2];
    float* out = (float*)d_out;
    char* ws = (char*)d_ws;

    // ws layout (bytes): Qs 8M | Kb 8M | Vt 8M | Opart 32M | lpart 64K
    u16* Qs = (u16*)(ws + 0);
    u16* Kb = (u16*)(ws + 8388608);
    u16* Vt = (u16*)(ws + 16777216);
    float* Op = (float*)(ws + 25165824);
    float* lp = (float*)(ws + 58720256);

    // scale = (2/sqrt(512)) * log2(e): P = exp2(s') == softmax(2s) numerator exactly
    const float scale = 0.12751743576842596f;
    cvt_kernel<<<4096, 256, 0, stream>>>(Q, Qs, 1048576, scale);
    cvt_kernel<<<4096, 256, 0, stream>>>(K, Kb, 1048576, 1.0f);
    prep_vt<<<dim3(128, 8), 256, 0, stream>>>(V, Vt);
    flash_kernel<<<256, 512, 0, stream>>>(Qs, Kb, Vt, Op, lp);
    combine_kernel<<<4096, 256, 0, stream>>>(Op, lp, out);
}